// Round 8
// baseline (92.099 us; speedup 1.0000x reference)
//
#include <hip/hip_runtime.h>
#include <hip/hip_bf16.h>

// Sizes
#define NB 8
#define NC 4
#define NN 1024
#define ND 96
#define NHH 3
#define DKV 32
#define NBC (NB*NC)        // 32
#define NHEAD (NBC*NHH)    // 96
#define NROWS (NBC*NN)     // 32768
// log2(e) / sqrt(32)  (folded into K at projection time)
#define C1 0.25503486910638953f
#define EPSV 1e-5f

using short8 = __attribute__((ext_vector_type(8))) short;
using f32x4  = __attribute__((ext_vector_type(4))) float;
using f32x16 = __attribute__((ext_vector_type(16))) float;

__device__ __forceinline__ short bf16_of(float f) {
  __hip_bfloat16 h = __float2bfloat16(f);
  return __builtin_bit_cast(short, h);
}
__device__ __forceinline__ float f_of_bf16(short s) {
  return __bfloat162float(__builtin_bit_cast(__hip_bfloat16, s));
}

__device__ __forceinline__ short8 load_cvt8(const float* p) {
  float4 f0 = *(const float4*)p;
  float4 f1 = *(const float4*)(p + 4);
  short8 v;
  v[0] = bf16_of(f0.x); v[1] = bf16_of(f0.y); v[2] = bf16_of(f0.z); v[3] = bf16_of(f0.w);
  v[4] = bf16_of(f1.x); v[5] = bf16_of(f1.y); v[6] = bf16_of(f1.z); v[7] = bf16_of(f1.w);
  return v;
}

// ---------------------------------------------------------------------------
// Kernel 1: projections, p split across blocks. W staged in LDS (reused by
// all waves); x loaded DIRECT from global (32B/lane, full line utilization).
// grid 1536 = 3 x 512, block 256.
// ---------------------------------------------------------------------------
__global__ __launch_bounds__(256) void proj_kernel(
    const float* __restrict__ xq, const float* __restrict__ xk, const float* __restrict__ xv,
    const float* __restrict__ Wq, const float* __restrict__ Wk, const float* __restrict__ Wv,
    short* __restrict__ qb, short* __restrict__ kb, short* __restrict__ vb)
{
  __shared__ __align__(16) short wlds[96][104];
  const int t = threadIdx.x;
  const int p = blockIdx.x >> 9;               // 0..2
  const int blkrow0 = (blockIdx.x & 511) * 64;

  const float* x = (p == 0) ? xq : (p == 1) ? xk : xv;
  const float* W = (p == 0) ? Wq : (p == 1) ? Wk : Wv;
  short* dst = (p == 0) ? qb : (p == 1) ? kb : vb;
  const float sc = (p == 1) ? C1 : 1.0f;

  for (int idx = t; idx < 96*96; idx += 256)
    wlds[idx/96][idx%96] = bf16_of(W[idx]);
  __syncthreads();

  const int wave = t >> 6, lane = t & 63;
  const int g = lane >> 4, li = lane & 15;
  const int row0 = blkrow0 + wave * 16;
  const int acol = g * 8;

  const float* xr = x + (size_t)(row0 + li)*ND + acol;
  const short8 a0 = load_cvt8(xr);
  const short8 a1 = load_cvt8(xr + 32);
  const short8 a2 = load_cvt8(xr + 64);
#pragma unroll
  for (int tt = 0; tt < 6; ++tt) {
    f32x4 acc = {0.f, 0.f, 0.f, 0.f};
    const short* wr = &wlds[tt*16 + li][acol];
    acc = __builtin_amdgcn_mfma_f32_16x16x32_bf16(a0, *(const short8*)(wr),      acc, 0, 0, 0);
    acc = __builtin_amdgcn_mfma_f32_16x16x32_bf16(a1, *(const short8*)(wr + 32), acc, 0, 0, 0);
    acc = __builtin_amdgcn_mfma_f32_16x16x32_bf16(a2, *(const short8*)(wr + 64), acc, 0, 0, 0);
    const int e = tt*16 + li;
    const int h = e >> 5, dd = e & 31;
#pragma unroll
    for (int r = 0; r < 4; ++r) {
      const int n = row0 + g*4 + r;
      const int bc = n >> 10, nn = n & 1023;
      const int head = bc*NHH + h;
      dst[((size_t)head*NN + nn)*DKV + dd] = bf16_of(acc[r] * sc);
    }
  }
}

// ---------------------------------------------------------------------------
// Kernel 2: column softmax sums + V' = diag(1/sum)*V transposed.
// Main loop: NO LDS, NO barriers — Q B-frags loaded direct from global
// (contiguous 1KB per MFMA, perfectly coalesced; L1/L2-hit via XCD swizzle:
// head = blockIdx%96 -> all 16 k-blocks of a head on one XCD).
// grid 96*16, block 256 (wave owns 16 k-rows).
// ---------------------------------------------------------------------------
__global__ __launch_bounds__(256) void stats_kernel(
    const short* __restrict__ qb, const short* __restrict__ kb,
    const short* __restrict__ vb, short* __restrict__ vtb)
{
  __shared__ float s_is[64];
  __shared__ __align__(16) short s_t[32][64];    // V' transpose buf (swizzled)

  const int t = threadIdx.x, wave = t >> 6, lane = t & 63;
  const int g = lane >> 4, li = lane & 15;
  const int head = blockIdx.x % NHEAD;           // XCD-aware
  const int kblk = blockIdx.x / NHEAD;           // 0..15
  const int kb0 = kblk*64;
  const int k0 = kb0 + wave*16;

  const short8 af = *(const short8*)(kb + ((size_t)head*NN + k0 + li)*DKV + g*8);
  const short* qB = qb + (size_t)head*NN*DKV + (size_t)li*DKV + g*8;

  f32x4 s0 = {0.f,0.f,0.f,0.f};
#pragma unroll 4
  for (int qt = 0; qt < 64; ++qt) {
    const short8 bf = *(const short8*)(qB + (size_t)qt*16*DKV);
    f32x4 z = {0.f,0.f,0.f,0.f};
    f32x4 d = __builtin_amdgcn_mfma_f32_16x16x32_bf16(af, bf, z, 0, 0, 0);
#pragma unroll
    for (int r = 0; r < 4; ++r)
      s0[r] += __builtin_amdgcn_exp2f(d[r]);
  }

#pragma unroll
  for (int ms = 1; ms <= 8; ms <<= 1) {
#pragma unroll
    for (int r = 0; r < 4; ++r)
      s0[r] += __shfl_xor(s0[r], ms);
  }
  if (li == 0) {
#pragma unroll
    for (int r = 0; r < 4; ++r)
      s_is[wave*16 + g*4 + r] = 1.0f / s0[r];
  }
  __syncthreads();

  // ---- V' phase A: read vb rows, scale by is[n], scatter into LDS transpose
  {
    const int nl = t >> 2;              // 0..63 (local k)
    const int dvs = (t & 3) * 8;        // dv segment base
    const float isv = s_is[nl];
    const short* vrow = vb + ((size_t)head*NN + kb0 + nl)*DKV + dvs;
    short8 v0 = *(const short8*)(vrow);
    short* st = &s_t[0][0];
#pragma unroll
    for (int j = 0; j < 8; ++j) {
      const int dv = dvs + j;
      st[dv*64 + (((nl*2) ^ ((dv & 7) << 4)) >> 1)] = bf16_of(isv * f_of_bf16(v0[j]));
    }
  }
  __syncthreads();

  // ---- V' phase B: coalesced write to vtb [head][dv][n]
  {
    const short* st = &s_t[0][0];
    const int dv = t >> 3, ns = t & 7;
    short8 v = *(const short8*)(st + dv*64 + (((ns*16) ^ ((dv & 7) << 4)) >> 1));
    *(short8*)(vtb + ((size_t)head*DKV + dv)*NN + kb0 + ns*8) = v;
  }
}

// ---------------------------------------------------------------------------
// Kernel 3: context. ZERO LDS, ZERO barriers. K/V' fragments loaded direct
// from global (L1-shared across the block's 4 waves; L2-resident per XCD).
// tau (swap bits 2<->3 of the A-row index) is folded into each lane's base
// address, so exp'd S^T regs ARE the PV A-fragments. 32 independent
// iterations -> compiler software-pipelines freely.
// grid 96*8, block 256 (4 waves x 32 q = 128 q per block).
// ---------------------------------------------------------------------------
__global__ __launch_bounds__(256) void ctx_kernel(
    const short* __restrict__ qb, const short* __restrict__ kb,
    const short* __restrict__ vtb, short* __restrict__ ctx)
{
  const int t = threadIdx.x, wave = t >> 6, lane = t & 63;
  const int li = lane & 31, hi = lane >> 5;
  const int head = blockIdx.x % NHEAD;             // XCD-aware
  const int qtile = blockIdx.x / NHEAD;            // 0..7
  const int q0 = qtile*128 + wave*32;

  const short* qrow = qb + ((size_t)head*NN + q0 + li)*DKV;
  const short8 qf0 = *(const short8*)(qrow + hi*8);
  const short8 qf1 = *(const short8*)(qrow + 16 + hi*8);

  // tau: swap bits 2,3 of li (involution) folded into the K base address
  const int rowA = (li & 19) | ((li & 4) << 1) | ((li & 8) >> 1);
  const short* kA = kb  + ((size_t)head*NN + rowA)*DKV + hi*8;
  const short* vA = vtb + ((size_t)head*DKV + li)*NN + hi*8;

  f32x16 acc = {0.f,0.f,0.f,0.f,0.f,0.f,0.f,0.f,0.f,0.f,0.f,0.f,0.f,0.f,0.f,0.f};

#pragma unroll 4
  for (int kc = 0; kc < 32; ++kc) {                // 32-k chunks
    const short8 a0  = *(const short8*)(kA + (size_t)kc*32*DKV);
    const short8 a1  = *(const short8*)(kA + (size_t)kc*32*DKV + 16);
    const short8 vfa = *(const short8*)(vA + kc*32);
    const short8 vfb = *(const short8*)(vA + kc*32 + 16);

    f32x16 sT = {0.f,0.f,0.f,0.f,0.f,0.f,0.f,0.f,0.f,0.f,0.f,0.f,0.f,0.f,0.f,0.f};
    sT = __builtin_amdgcn_mfma_f32_32x32x16_bf16(a0, qf0, sT, 0, 0, 0);
    sT = __builtin_amdgcn_mfma_f32_32x32x16_bf16(a1, qf1, sT, 0, 0, 0);

    short8 pa0, pa1;
#pragma unroll
    for (int j = 0; j < 8; ++j) {
      pa0[j] = bf16_of(__builtin_amdgcn_exp2f(sT[j]));
      pa1[j] = bf16_of(__builtin_amdgcn_exp2f(sT[8 + j]));
    }
    acc = __builtin_amdgcn_mfma_f32_32x32x16_bf16(pa0, vfa, acc, 0, 0, 0);
    acc = __builtin_amdgcn_mfma_f32_32x32x16_bf16(pa1, vfb, acc, 0, 0, 0);
  }

  const int bc = head / NHH, h = head % NHH;
#pragma unroll
  for (int reg = 0; reg < 16; ++reg) {
    const int q = q0 + (reg & 3) + 8*(reg >> 2) + 4*hi;
    ctx[((size_t)(bc*NN + q))*ND + h*DKV + li] = bf16_of(acc[reg]);
  }
}

// ---------------------------------------------------------------------------
// Kernel 4: out = LN(ctx @ Wfc^T + input_Q).
// ---------------------------------------------------------------------------
__global__ __launch_bounds__(256) void out_kernel(
    const short* __restrict__ ctx, const float* __restrict__ Wfc,
    const float* __restrict__ resid, const float* __restrict__ gamma,
    const float* __restrict__ beta, float* __restrict__ out)
{
  __shared__ __align__(16) short wlds[96][104];
  const int t = threadIdx.x;
  for (int idx = t; idx < 96*96; idx += 256)
    wlds[idx/96][idx%96] = bf16_of(Wfc[idx]);
  __syncthreads();

  const int wave = t >> 6, lane = t & 63;
  const int g = lane >> 4, li = lane & 15;
  const int row0 = blockIdx.x * 64 + wave * 16;

  const short* ar = ctx + (size_t)(row0 + li)*ND + g*8;
  const short8 a0 = *(const short8*)(ar);
  const short8 a1 = *(const short8*)(ar + 32);
  const short8 a2 = *(const short8*)(ar + 64);

  float o[6][4];
#pragma unroll
  for (int tt = 0; tt < 6; ++tt) {
    f32x4 acc = {0.f, 0.f, 0.f, 0.f};
    const short* wr = &wlds[tt*16 + li][g*8];
    acc = __builtin_amdgcn_mfma_f32_16x16x32_bf16(a0, *(const short8*)(wr),      acc, 0, 0, 0);
    acc = __builtin_amdgcn_mfma_f32_16x16x32_bf16(a1, *(const short8*)(wr + 32), acc, 0, 0, 0);
    acc = __builtin_amdgcn_mfma_f32_16x16x32_bf16(a2, *(const short8*)(wr + 64), acc, 0, 0, 0);
#pragma unroll
    for (int r = 0; r < 4; ++r)
      o[tt][r] = acc[r] + resid[(size_t)(row0 + g*4 + r)*ND + tt*16 + li];
  }

  float s1v[4], s2v[4];
#pragma unroll
  for (int r = 0; r < 4; ++r) {
    float a = 0.f, b = 0.f;
#pragma unroll
    for (int tt = 0; tt < 6; ++tt) { a += o[tt][r]; b += o[tt][r]*o[tt][r]; }
    s1v[r] = a; s2v[r] = b;
  }
#pragma unroll
  for (int ms = 1; ms <= 8; ms <<= 1) {
#pragma unroll
    for (int r = 0; r < 4; ++r) {
      s1v[r] += __shfl_xor(s1v[r], ms);
      s2v[r] += __shfl_xor(s2v[r], ms);
    }
  }
  float mean[4], rs[4];
#pragma unroll
  for (int r = 0; r < 4; ++r) {
    mean[r] = s1v[r] * (1.0f/96.0f);
    float var = s2v[r]*(1.0f/96.0f) - mean[r]*mean[r];
    rs[r] = rsqrtf(var + EPSV);
  }
#pragma unroll
  for (int tt = 0; tt < 6; ++tt) {
    const int e = tt*16 + li;
    const float gg = gamma[e], bb = beta[e];
#pragma unroll
    for (int r = 0; r < 4; ++r)
      out[(size_t)(row0 + g*4 + r)*ND + e] = (o[tt][r] - mean[r])*rs[r]*gg + bb;
  }
}

// ---------------------------------------------------------------------------
extern "C" void kernel_launch(void* const* d_in, const int* in_sizes, int n_in,
                              void* d_out, int out_size, void* d_ws, size_t ws_size,
                              hipStream_t stream) {
  (void)in_sizes; (void)n_in; (void)out_size; (void)ws_size;
  const float* xq    = (const float*)d_in[0];
  const float* xk    = (const float*)d_in[1];
  const float* xv    = (const float*)d_in[2];
  const float* Wq    = (const float*)d_in[3];
  const float* Wk    = (const float*)d_in[4];
  const float* Wv    = (const float*)d_in[5];
  const float* Wfc   = (const float*)d_in[6];
  const float* gamma = (const float*)d_in[7];
  const float* beta  = (const float*)d_in[8];
  float* out = (float*)d_out;

  // Workspace layout (25.17 MB total — ctx aliases vb, dead after stats;
  // proven safe since round 4).
  short* qb  = (short*)d_ws;                         // [head][n][32]
  short* kb  = qb  + (size_t)NHEAD*NN*DKV;           // [head][n][32] (x C1)
  short* vtb = kb  + (size_t)NHEAD*NN*DKV;           // [head][32][n] = is[k]*V
  short* vb  = vtb + (size_t)NHEAD*NN*DKV;           // [head][n][32] (dead after stats)
  short* ctx = vb;                                   // [bc*n][96] (aliases vb)

  hipLaunchKernelGGL(proj_kernel,  dim3(3*NROWS/64), dim3(256), 0, stream,
                     xq, xk, xv, Wq, Wk, Wv, qb, kb, vb);
  hipLaunchKernelGGL(stats_kernel, dim3(NHEAD*16), dim3(256), 0, stream,
                     qb, kb, vb, vtb);
  hipLaunchKernelGGL(ctx_kernel,   dim3(NHEAD*8), dim3(256), 0, stream,
                     qb, kb, vtb, ctx);
  hipLaunchKernelGGL(out_kernel,   dim3(NROWS/64), dim3(256), 0, stream,
                     ctx, Wfc, xq, gamma, beta, out);
}